// Round 12
// baseline (716.285 us; speedup 1.0000x reference)
//
#include <hip/hip_runtime.h>
#include <hip/hip_bf16.h>
#include <cstdint>

// ---------------------------------------------------------------------------
// MolGraphEncoder r12: r11 + register-resident CSR window in k_fused.
// Strip edge indices loaded lane-parallel (coalesced) into a 128-edge rolling
// window (2 VGPRs); per-edge index via __shfl. Removes the per-bucket csr
// round-trip and all uniform-address csr loads from the gather critical path.
// ---------------------------------------------------------------------------

typedef __attribute__((ext_vector_type(8))) short short8;
typedef __attribute__((ext_vector_type(4))) float f32x4;

__device__ __forceinline__ float b2f(unsigned int hi16) {
    return __builtin_bit_cast(float, hi16);
}
__device__ __forceinline__ unsigned short f2b(float f) {  // RTN-even
    unsigned int u = __builtin_bit_cast(unsigned int, f);
    u += 0x7fffu + ((u >> 16) & 1u);
    return (unsigned short)(u >> 16);
}
__device__ __forceinline__ unsigned int packbf(float lo, float hi) {
    return ((unsigned int)f2b(hi) << 16) | f2b(lo);
}

__global__ void k_count(const int* __restrict__ dst, int* __restrict__ cnt, int E) {
    int e = blockIdx.x * blockDim.x + threadIdx.x;
    if (e < E) atomicAdd(&cnt[dst[e]], 1);
}

// --- scan (2048/block) + fused dis = rsqrt(deg+1) ---------------------------
__global__ void k_scan1(const int* __restrict__ in, int* __restrict__ out1,
                        int* __restrict__ bsum, float* __restrict__ dis, int n) {
    __shared__ int s[256];
    int t = threadIdx.x;
    int base = blockIdx.x * 2048 + t * 8;
    int v[8];
    int run = 0;
#pragma unroll
    for (int i = 0; i < 8; ++i) {
        int idx = base + i;
        int x = (idx < n) ? in[idx] : 0;
        if (idx < n) dis[idx] = rsqrtf((float)x + 1.0f);
        run += x;
        v[i] = run;
    }
    s[t] = run;
    __syncthreads();
    for (int off = 1; off < 256; off <<= 1) {
        int add = (t >= off) ? s[t - off] : 0;
        __syncthreads();
        s[t] += add;
        __syncthreads();
    }
    int pre = (t > 0) ? s[t - 1] : 0;
#pragma unroll
    for (int i = 0; i < 8; ++i) {
        int idx = base + i;
        if (idx < n) out1[idx] = v[i] + pre;
    }
    if (t == 255) bsum[blockIdx.x] = s[255];
}

// scan3 with internal bsum-prefix reduction (replaces scan2+scan3)
__global__ void k_scan3(int* __restrict__ rowstart, const int* __restrict__ bsum, int n) {
    int b = blockIdx.x, t = threadIdx.x;
    if (b == 0) {
        if (t == 0) rowstart[0] = 0;
        return;
    }
    __shared__ int ws[4];
    int v = (t < b) ? bsum[t] : 0;  // nb <= 256 guaranteed by launch config
#pragma unroll
    for (int off = 32; off; off >>= 1) v += __shfl_xor(v, off);
    if ((t & 63) == 0) ws[t >> 6] = v;
    __syncthreads();
    int add = ws[0] + ws[1] + ws[2] + ws[3];
    int* out1 = rowstart + 1;
    int base = b * 2048 + t * 8;
#pragma unroll
    for (int i = 0; i < 8; ++i) {
        int idx = base + i;
        if (idx < n) out1[idx] += add;
    }
}

// fill CSR: position = rowstart[d] + zero-based atomic offset
__global__ void k_fill(const int* __restrict__ src, const int* __restrict__ dst,
                       const int* __restrict__ rowstart, int* __restrict__ cur0,
                       int* __restrict__ csr_src, int E) {
    int e = blockIdx.x * blockDim.x + threadIdx.x;
    if (e >= E) return;
    int d = dst[e];
    int pos = rowstart[d] + atomicAdd(&cur0[d], 1);
    csr_src[pos] = src[e];
}

// --- pack all 3 weights into MFMA B-fragment layout (bf16, K padded) --------
__global__ void k_cvtw3(const float* __restrict__ W0, const float* __restrict__ W1,
                        const float* __restrict__ W2, unsigned short* __restrict__ wp0,
                        unsigned short* __restrict__ wp1, unsigned short* __restrict__ wp2) {
    int tid = blockIdx.x * blockDim.x + threadIdx.x;
    const float* W;
    unsigned short* o;
    int Ksrc, f;
    if (tid < 3 * 512) { W = W0; o = wp0; Ksrc = 82; f = tid; }
    else if (tid < 7 * 512) { W = W1; o = wp1; Ksrc = 128; f = tid - 3 * 512; }
    else if (tid < 11 * 512) { W = W2; o = wp2; Ksrc = 128; f = tid - 7 * 512; }
    else return;
    int lane = f & 63, fr = f >> 6;
    int m = fr >> 3, ct = fr & 7;
    int col = ct * 16 + (lane & 15);
    int kb = m * 32 + ((lane >> 4) << 3);
    unsigned short v[8];
#pragma unroll
    for (int j = 0; j < 8; ++j) {
        int k = kb + j;
        v[j] = (k < Ksrc) ? f2b(W[k * 128 + col]) : (unsigned short)0;
    }
    *(short8*)(o + (size_t)f * 8) = *(short8*)v;
}

// --- xd = bf16(dis[v]*x[v]) padded to 96 cols; 4 u32 slots per thread -------
__global__ __launch_bounds__(256) void k_xd(const float* __restrict__ x,
                                            const float* __restrict__ dis,
                                            unsigned int* __restrict__ xd, int n) {
    int tid = blockIdx.x * blockDim.x + threadIdx.x;
    if (tid >= n * 12) return;
    int v = tid / 12;
    int j = tid - v * 12;  // 0..11, covers slots 4j..4j+3
    float dv = dis[v];
    const float* xv = x + (size_t)v * 82;
    int s0 = 4 * j;
    float2 t0 = (s0 + 0 <= 40) ? *(const float2*)(xv + 2 * (s0 + 0)) : make_float2(0.f, 0.f);
    float2 t1 = (s0 + 1 <= 40) ? *(const float2*)(xv + 2 * (s0 + 1)) : make_float2(0.f, 0.f);
    float2 t2 = (s0 + 2 <= 40) ? *(const float2*)(xv + 2 * (s0 + 2)) : make_float2(0.f, 0.f);
    float2 t3 = (s0 + 3 <= 40) ? *(const float2*)(xv + 2 * (s0 + 3)) : make_float2(0.f, 0.f);
    uint4 o;
    o.x = packbf(dv * t0.x, dv * t0.y);
    o.y = packbf(dv * t1.x, dv * t1.y);
    o.z = packbf(dv * t2.x, dv * t2.y);
    o.w = packbf(dv * t3.x, dv * t3.y);
    ((uint4*)(xd + (size_t)v * 48))[j] = o;
}

// --- fused GCN layer, single-wave block, register-resident CSR window -------
// Input rows: RU = KS*16 u32 (2 bf16 each), dis-prescaled by producer.
// agg[v] = dis[v] * ( in[v] + sum_{u->v} in[u] );  out = relu(agg @ W + b)
template <int KS, bool SCALE, bool GATE>
__global__ __launch_bounds__(64, 8) void k_fused(
    const unsigned int* __restrict__ hd, const float* __restrict__ dis,
    const int* __restrict__ rowstart, const int* __restrict__ csr,
    const unsigned short* __restrict__ Wp, const float* __restrict__ bias,
    unsigned short* __restrict__ out, const float* __restrict__ gw,
    const float* __restrict__ gb, float* __restrict__ gate, int n) {
    constexpr int RU = KS * 16;  // u32 per input row
    __shared__ unsigned int As[16 * 64];  // 16 rows x 256B (zero-padded), swizzled
    int lane = threadIdx.x & 63;
    int tile = blockIdx.x * 16;
    const bool act = (RU == 64) ? true : (lane < RU);
    const int li = act ? lane : 0;

    // hoisted strip bounds (wave-uniform; 17 ints)
    int bb[17];
#pragma unroll
    for (int i = 0; i < 17; ++i) {
        int idx = tile + i;
        bb[i] = rowstart[idx < n ? idx : n];
    }
    const int el = bb[0], eh = bb[16];

    // 128-edge rolling CSR window, lane-distributed (coalesced loads)
    int wbase = el;
    unsigned int wA = (wbase + lane < eh) ? (unsigned int)csr[wbase + lane] : 0u;
    unsigned int wB = (wbase + 64 + lane < eh) ? (unsigned int)csr[wbase + 64 + lane] : 0u;

    // ---- phase 1: gather 16 rows as 4 buckets of 4 (8-edge ILP) ----
#pragma unroll
    for (int g = 0; g < 4; ++g) {
        int r = g * 4;
        int v0 = tile + r;
        unsigned int* dst0 = &As[(r + 0) * 64 + (lane ^ (((r + 0) & 7) << 2))];
        unsigned int* dst1 = &As[(r + 1) * 64 + (lane ^ (((r + 1) & 7) << 2))];
        unsigned int* dst2 = &As[(r + 2) * 64 + (lane ^ (((r + 2) & 7) << 2))];
        unsigned int* dst3 = &As[(r + 3) * 64 + (lane ^ (((r + 3) & 7) << 2))];
        if (v0 >= n) {
            *dst0 = 0u; *dst1 = 0u; *dst2 = 0u; *dst3 = 0u;
            continue;
        }
        int nv = n - v0;
        if (nv > 4) nv = 4;
        int e0 = bb[r], eE = bb[r + nv];
        int b1 = (nv > 1) ? bb[r + 1] : eE;
        int b2 = (nv > 2) ? bb[r + 2] : eE;
        int b3 = (nv > 3) ? bb[r + 3] : eE;

        unsigned int s0 = hd[(size_t)v0 * RU + li];
        unsigned int s1 = (nv > 1) ? hd[(size_t)(v0 + 1) * RU + li] : 0u;
        unsigned int s2 = (nv > 2) ? hd[(size_t)(v0 + 2) * RU + li] : 0u;
        unsigned int s3 = (nv > 3) ? hd[(size_t)(v0 + 3) * RU + li] : 0u;
        float a0x = b2f(s0 << 16), a0y = b2f(s0 & 0xffff0000u);
        float a1x = b2f(s1 << 16), a1y = b2f(s1 & 0xffff0000u);
        float a2x = b2f(s2 << 16), a2y = b2f(s2 & 0xffff0000u);
        float a3x = b2f(s3 << 16), a3y = b2f(s3 & 0xffff0000u);

        for (int e = e0; e < eE; e += 8) {
            // keep e..e+7 inside [wbase, wbase+128)
            while (e + 8 > wbase + 128) {
                wbase += 64;
                wA = wB;
                wB = (wbase + 64 + lane < eh) ? (unsigned int)csr[wbase + 64 + lane] : 0u;
            }
            int rem = eE - e;
            // indices via shfl from the register window (uniform lane index)
#define IDX(K)                                                              \
            ({                                                              \
                int ek_ = (rem > (K)) ? e + (K) : e;                        \
                int off_ = ek_ - wbase;                                     \
                (int)__shfl((off_ < 64) ? wA : wB, off_ & 63);              \
            })
            int u0 = IDX(0), u1 = IDX(1), u2 = IDX(2), u3 = IDX(3);
            int u4 = IDX(4), u5 = IDX(5), u6 = IDX(6), u7 = IDX(7);
#undef IDX
            unsigned int r0v = hd[(size_t)u0 * RU + li];
            unsigned int r1v = hd[(size_t)u1 * RU + li];
            unsigned int r2v = hd[(size_t)u2 * RU + li];
            unsigned int r3v = hd[(size_t)u3 * RU + li];
            unsigned int r4v = hd[(size_t)u4 * RU + li];
            unsigned int r5v = hd[(size_t)u5 * RU + li];
            unsigned int r6v = hd[(size_t)u6 * RU + li];
            unsigned int r7v = hd[(size_t)u7 * RU + li];
#define ACC(rv, ei)                                                     \
            {                                                           \
                float fx = b2f((rv) << 16), fy = b2f((rv) & 0xffff0000u); \
                if ((ei) < b1) { a0x += fx; a0y += fy; }                \
                else if ((ei) < b2) { a1x += fx; a1y += fy; }           \
                else if ((ei) < b3) { a2x += fx; a2y += fy; }           \
                else { a3x += fx; a3y += fy; }                          \
            }
            ACC(r0v, e)
            if (rem > 1) ACC(r1v, e + 1)
            if (rem > 2) ACC(r2v, e + 2)
            if (rem > 3) ACC(r3v, e + 3)
            if (rem > 4) ACC(r4v, e + 4)
            if (rem > 5) ACC(r5v, e + 5)
            if (rem > 6) ACC(r6v, e + 6)
            if (rem > 7) ACC(r7v, e + 7)
#undef ACC
        }

        float d0 = dis[v0];
        float d1 = (nv > 1) ? dis[v0 + 1] : 0.f;
        float d2 = (nv > 2) ? dis[v0 + 2] : 0.f;
        float d3 = (nv > 3) ? dis[v0 + 3] : 0.f;
        *dst0 = act ? packbf(d0 * a0x, d0 * a0y) : 0u;
        *dst1 = (act && nv > 1) ? packbf(d1 * a1x, d1 * a1y) : 0u;
        *dst2 = (act && nv > 2) ? packbf(d2 * a2x, d2 * a2y) : 0u;
        *dst3 = (act && nv > 3) ? packbf(d3 * a3x, d3 * a3y) : 0u;
    }
    // single wave: LDS writes visible after s_waitcnt; no barrier needed

    // ---- phase 2: MFMA on the 16-row tile ----
    int r0 = lane & 15, ch = lane >> 4;
    const unsigned int* arow = &As[r0 << 6];
    f32x4 acc[8];
#pragma unroll
    for (int ct = 0; ct < 8; ++ct) acc[ct] = (f32x4){0.f, 0.f, 0.f, 0.f};
#pragma unroll
    for (int m = 0; m < KS; ++m) {
        int slot = (ch + 4 * m) ^ (r0 & 7);
        short8 a = *(const short8*)(arow + slot * 4);
        const short8* wf = (const short8*)Wp + ((size_t)(m * 8) * 64 + lane);
#pragma unroll
        for (int ct = 0; ct < 8; ++ct) {
            short8 b = wf[ct * 64];
            acc[ct] = __builtin_amdgcn_mfma_f32_16x16x32_bf16(a, b, acc[ct], 0, 0, 0);
        }
    }

    // ---- epilogue ----
    float bbv[8], gwv[8];
#pragma unroll
    for (int ct = 0; ct < 8; ++ct) {
        bbv[ct] = bias[ct * 16 + r0];
        if (GATE) gwv[ct] = gw[ct * 16 + r0];
    }
    float gbv = GATE ? gb[0] : 0.f;
    int rbase = tile + (ch << 2);
#pragma unroll
    for (int reg = 0; reg < 4; ++reg) {
        int row = rbase + reg;
        bool ok = row < n;
        float dv = (SCALE && ok) ? dis[row] : 1.f;
        float gp = 0.f;
#pragma unroll
        for (int ct = 0; ct < 8; ++ct) {
            float o = fmaxf(acc[ct][reg] + bbv[ct], 0.f);
            if (GATE) gp = fmaf(o, gwv[ct], gp);
            if (ok) out[(size_t)row * 128 + ct * 16 + r0] = f2b(SCALE ? o * dv : o);
        }
        if (GATE) {
            gp += __shfl_xor(gp, 1);
            gp += __shfl_xor(gp, 2);
            gp += __shfl_xor(gp, 4);
            gp += __shfl_xor(gp, 8);
            if (r0 == 0 && ok) gate[row] = gp + gbv;
        }
    }
}

// --- attention pooling: one wave per graph, inline bounds, ILP-4 sum --------
__global__ __launch_bounds__(256) void k_pool(const unsigned short* __restrict__ h,
                                              const float* __restrict__ gate,
                                              const int* __restrict__ batch,
                                              float* __restrict__ emb, int n, int B) {
    int wid = (blockIdx.x * blockDim.x + threadIdx.x) >> 6;
    int lane = threadIdx.x & 63;
    if (wid >= B) return;
    int bnd = 0;
    if (lane < 2) {
        int g = wid + lane;
        int lo = 0, hi = n;
        while (lo < hi) {
            int mid = (lo + hi) >> 1;
            if (batch[mid] < g) lo = mid + 1;
            else hi = mid;
        }
        bnd = lo;
    }
    int s = __shfl(bnd, 0), e2 = __shfl(bnd, 1);
    float* ev2 = emb + (size_t)wid * 128 + lane * 2;
    if (s >= e2) {
        ev2[0] = 0.f;
        ev2[1] = 0.f;
        return;
    }
    float m = -INFINITY;
    for (int v = s + lane; v < e2; v += 64) m = fmaxf(m, gate[v]);
#pragma unroll
    for (int off = 32; off; off >>= 1) m = fmaxf(m, __shfl_xor(m, off));
    float a0 = 0.f, a1 = 0.f, den = 0.f;
    const unsigned int* h32 = (const unsigned int*)h;
    int v = s;
    for (; v + 4 <= e2; v += 4) {
        float g0 = gate[v], g1 = gate[v + 1], g2 = gate[v + 2], g3 = gate[v + 3];
        unsigned int h0 = h32[(size_t)(v + 0) * 64 + lane];
        unsigned int h1 = h32[(size_t)(v + 1) * 64 + lane];
        unsigned int h2 = h32[(size_t)(v + 2) * 64 + lane];
        unsigned int h3 = h32[(size_t)(v + 3) * 64 + lane];
        float e0 = __expf(g0 - m), e1 = __expf(g1 - m);
        float e2v = __expf(g2 - m), e3 = __expf(g3 - m);
        den += (e0 + e1) + (e2v + e3);
        a0 = fmaf(e0, b2f(h0 << 16), a0);
        a1 = fmaf(e0, b2f(h0 & 0xffff0000u), a1);
        a0 = fmaf(e1, b2f(h1 << 16), a0);
        a1 = fmaf(e1, b2f(h1 & 0xffff0000u), a1);
        a0 = fmaf(e2v, b2f(h2 << 16), a0);
        a1 = fmaf(e2v, b2f(h2 & 0xffff0000u), a1);
        a0 = fmaf(e3, b2f(h3 << 16), a0);
        a1 = fmaf(e3, b2f(h3 & 0xffff0000u), a1);
    }
    for (; v < e2; ++v) {
        float ev = __expf(gate[v] - m);
        den += ev;
        unsigned int hv = h32[(size_t)v * 64 + lane];
        a0 = fmaf(ev, b2f(hv << 16), a0);
        a1 = fmaf(ev, b2f(hv & 0xffff0000u), a1);
    }
    float inv = 1.f / den;
    ev2[0] = a0 * inv;
    ev2[1] = a1 * inv;
}

// --- final projection: 32 graphs per block ----------------------------------
__global__ __launch_bounds__(256) void k_proj(const float* __restrict__ emb,
                                              const float* __restrict__ pw,
                                              const float* __restrict__ pb,
                                              float* __restrict__ out, int B) {
    __shared__ float es[32][128];
    int g0 = blockIdx.x * 32;
    int t = threadIdx.x;
    for (int i = t; i < 1024; i += 256) {
        int g = g0 + (i >> 5);
        float4 val = (g < B) ? ((const float4*)emb)[(size_t)g * 32 + (i & 31)]
                             : make_float4(0.f, 0.f, 0.f, 0.f);
        *(float4*)&es[i >> 5][(i & 31) * 4] = val;
    }
    __syncthreads();
    float acc[32];
#pragma unroll
    for (int i = 0; i < 32; ++i) acc[i] = 0.f;
    for (int k = 0; k < 128; ++k) {
        float wv = pw[k * 256 + t];
#pragma unroll
        for (int i = 0; i < 32; ++i) acc[i] = fmaf(es[i][k], wv, acc[i]);
    }
    float b = pb[t];
#pragma unroll
    for (int i = 0; i < 32; ++i) {
        int g = g0 + i;
        if (g < B) out[(size_t)g * 256 + t] = acc[i] + b;
    }
}

// ---------------------------------------------------------------------------
extern "C" void kernel_launch(void* const* d_in, const int* in_sizes, int n_in,
                              void* d_out, int out_size, void* d_ws, size_t ws_size,
                              hipStream_t stream) {
    const float* x = (const float*)d_in[0];
    const int* ei = (const int*)d_in[1];
    const int* batch = (const int*)d_in[2];
    const float* W0 = (const float*)d_in[3];
    const float* b0 = (const float*)d_in[4];
    const float* W1 = (const float*)d_in[5];
    const float* b1 = (const float*)d_in[6];
    const float* W2 = (const float*)d_in[7];
    const float* b2 = (const float*)d_in[8];
    const float* gw = (const float*)d_in[9];
    const float* gb = (const float*)d_in[10];
    const float* pw = (const float*)d_in[11];
    const float* pb = (const float*)d_in[12];
    float* out = (float*)d_out;

    const int N = in_sizes[2];
    const int E = in_sizes[1] / 2;
    const int B = out_size / 256;
    (void)n_in;

    const int* esrc = ei;
    const int* edst = ei + E;

    char* p = (char*)d_ws;
    auto carve = [&](size_t bytes) {
        char* r = p;
        p += (bytes + 255) & ~(size_t)255;
        return r;
    };
    unsigned int* xd = (unsigned int*)carve((size_t)N * 48 * 4);
    unsigned int* hA = (unsigned int*)carve((size_t)N * 64 * 4);
    unsigned int* hB = (unsigned int*)carve((size_t)N * 64 * 4);
    float* emb = (float*)carve((size_t)B * 128 * 4);
    int* csr_src = (int*)carve((size_t)E * 4);
    float* dis = (float*)carve((size_t)N * 4);
    int* cnt = (int*)carve((size_t)2 * N * 4);  // cnt + cur0 (one memset)
    int* cur0 = cnt + N;
    int* rowstart = (int*)carve((size_t)(N + 1) * 4);
    float* gate = (float*)carve((size_t)N * 4);
    int* bsum = (int*)carve((size_t)4096 * 4);
    unsigned short* wp0 = (unsigned short*)carve((size_t)3 * 512 * 8 * 2);
    unsigned short* wp1 = (unsigned short*)carve((size_t)4 * 512 * 8 * 2);
    unsigned short* wp2 = (unsigned short*)carve((size_t)4 * 512 * 8 * 2);
    if ((size_t)(p - (char*)d_ws) > ws_size) return;

    const int nb = (N + 2047) / 2048;  // 245 (<= 256 required by k_scan3)

    hipMemsetAsync(cnt, 0, (size_t)2 * N * 4, stream);
    k_count<<<(E + 255) / 256, 256, 0, stream>>>(edst, cnt, E);
    k_scan1<<<nb, 256, 0, stream>>>(cnt, rowstart + 1, bsum, dis, N);
    k_scan3<<<nb, 256, 0, stream>>>(rowstart, bsum, N);
    k_fill<<<(E + 255) / 256, 256, 0, stream>>>(esrc, edst, rowstart, cur0, csr_src, E);
    k_cvtw3<<<22, 256, 0, stream>>>(W0, W1, W2, wp0, wp1, wp2);
    k_xd<<<(N * 12 + 255) / 256, 256, 0, stream>>>(x, dis, xd, N);

    const int fb = (N + 15) / 16;  // single-wave blocks, 16 rows each

    // layer 0: xd -> hA (bf16, dis-prescaled)
    k_fused<3, true, false><<<fb, 64, 0, stream>>>(
        xd, dis, rowstart, csr_src, wp0, b0, (unsigned short*)hA,
        nullptr, nullptr, nullptr, N);
    // layer 1: hA -> hB (bf16, dis-prescaled)
    k_fused<4, true, false><<<fb, 64, 0, stream>>>(
        hA, dis, rowstart, csr_src, wp1, b1, (unsigned short*)hB,
        nullptr, nullptr, nullptr, N);
    // layer 2: hB -> hA (unscaled) + gate
    k_fused<4, false, true><<<fb, 64, 0, stream>>>(
        hB, dis, rowstart, csr_src, wp2, b2, (unsigned short*)hA,
        gw, gb, gate, N);

    // pooling + projection
    k_pool<<<(B + 3) / 4, 256, 0, stream>>>((const unsigned short*)hA, gate, batch,
                                            emb, N, B);
    k_proj<<<(B + 31) / 32, 256, 0, stream>>>(emb, pw, pb, out, B);
}

// Round 13
// 566.448 us; speedup vs baseline: 1.2645x; 1.2645x over previous
//
#include <hip/hip_runtime.h>
#include <hip/hip_bf16.h>
#include <cstdint>

// ---------------------------------------------------------------------------
// MolGraphEncoder r13: r11 + csr register window ONLY (no bounds hoist — r12's
// bb[r+nv] runtime index spilled to scratch). Per-bucket rowstart loads kept.
// Window: 128 edges lane-distributed in 2 VGPRs, __shfl extraction, coalesced
// refill every 64 edges.
// ---------------------------------------------------------------------------

typedef __attribute__((ext_vector_type(8))) short short8;
typedef __attribute__((ext_vector_type(4))) float f32x4;

__device__ __forceinline__ float b2f(unsigned int hi16) {
    return __builtin_bit_cast(float, hi16);
}
__device__ __forceinline__ unsigned short f2b(float f) {  // RTN-even
    unsigned int u = __builtin_bit_cast(unsigned int, f);
    u += 0x7fffu + ((u >> 16) & 1u);
    return (unsigned short)(u >> 16);
}
__device__ __forceinline__ unsigned int packbf(float lo, float hi) {
    return ((unsigned int)f2b(hi) << 16) | f2b(lo);
}

__global__ void k_count(const int* __restrict__ dst, int* __restrict__ cnt, int E) {
    int e = blockIdx.x * blockDim.x + threadIdx.x;
    if (e < E) atomicAdd(&cnt[dst[e]], 1);
}

// --- scan (2048/block) + fused dis = rsqrt(deg+1) ---------------------------
__global__ void k_scan1(const int* __restrict__ in, int* __restrict__ out1,
                        int* __restrict__ bsum, float* __restrict__ dis, int n) {
    __shared__ int s[256];
    int t = threadIdx.x;
    int base = blockIdx.x * 2048 + t * 8;
    int v[8];
    int run = 0;
#pragma unroll
    for (int i = 0; i < 8; ++i) {
        int idx = base + i;
        int x = (idx < n) ? in[idx] : 0;
        if (idx < n) dis[idx] = rsqrtf((float)x + 1.0f);
        run += x;
        v[i] = run;
    }
    s[t] = run;
    __syncthreads();
    for (int off = 1; off < 256; off <<= 1) {
        int add = (t >= off) ? s[t - off] : 0;
        __syncthreads();
        s[t] += add;
        __syncthreads();
    }
    int pre = (t > 0) ? s[t - 1] : 0;
#pragma unroll
    for (int i = 0; i < 8; ++i) {
        int idx = base + i;
        if (idx < n) out1[idx] = v[i] + pre;
    }
    if (t == 255) bsum[blockIdx.x] = s[255];
}

// scan3 with internal bsum-prefix reduction (replaces scan2+scan3)
__global__ void k_scan3(int* __restrict__ rowstart, const int* __restrict__ bsum, int n) {
    int b = blockIdx.x, t = threadIdx.x;
    if (b == 0) {
        if (t == 0) rowstart[0] = 0;
        return;
    }
    __shared__ int ws[4];
    int v = (t < b) ? bsum[t] : 0;  // nb <= 256 guaranteed by launch config
#pragma unroll
    for (int off = 32; off; off >>= 1) v += __shfl_xor(v, off);
    if ((t & 63) == 0) ws[t >> 6] = v;
    __syncthreads();
    int add = ws[0] + ws[1] + ws[2] + ws[3];
    int* out1 = rowstart + 1;
    int base = b * 2048 + t * 8;
#pragma unroll
    for (int i = 0; i < 8; ++i) {
        int idx = base + i;
        if (idx < n) out1[idx] += add;
    }
}

// fill CSR: position = rowstart[d] + zero-based atomic offset
__global__ void k_fill(const int* __restrict__ src, const int* __restrict__ dst,
                       const int* __restrict__ rowstart, int* __restrict__ cur0,
                       int* __restrict__ csr_src, int E) {
    int e = blockIdx.x * blockDim.x + threadIdx.x;
    if (e >= E) return;
    int d = dst[e];
    int pos = rowstart[d] + atomicAdd(&cur0[d], 1);
    csr_src[pos] = src[e];
}

// --- pack all 3 weights into MFMA B-fragment layout (bf16, K padded) --------
__global__ void k_cvtw3(const float* __restrict__ W0, const float* __restrict__ W1,
                        const float* __restrict__ W2, unsigned short* __restrict__ wp0,
                        unsigned short* __restrict__ wp1, unsigned short* __restrict__ wp2) {
    int tid = blockIdx.x * blockDim.x + threadIdx.x;
    const float* W;
    unsigned short* o;
    int Ksrc, f;
    if (tid < 3 * 512) { W = W0; o = wp0; Ksrc = 82; f = tid; }
    else if (tid < 7 * 512) { W = W1; o = wp1; Ksrc = 128; f = tid - 3 * 512; }
    else if (tid < 11 * 512) { W = W2; o = wp2; Ksrc = 128; f = tid - 7 * 512; }
    else return;
    int lane = f & 63, fr = f >> 6;
    int m = fr >> 3, ct = fr & 7;
    int col = ct * 16 + (lane & 15);
    int kb = m * 32 + ((lane >> 4) << 3);
    unsigned short v[8];
#pragma unroll
    for (int j = 0; j < 8; ++j) {
        int k = kb + j;
        v[j] = (k < Ksrc) ? f2b(W[k * 128 + col]) : (unsigned short)0;
    }
    *(short8*)(o + (size_t)f * 8) = *(short8*)v;
}

// --- xd = bf16(dis[v]*x[v]) padded to 96 cols; 4 u32 slots per thread -------
__global__ __launch_bounds__(256) void k_xd(const float* __restrict__ x,
                                            const float* __restrict__ dis,
                                            unsigned int* __restrict__ xd, int n) {
    int tid = blockIdx.x * blockDim.x + threadIdx.x;
    if (tid >= n * 12) return;
    int v = tid / 12;
    int j = tid - v * 12;  // 0..11, covers slots 4j..4j+3
    float dv = dis[v];
    const float* xv = x + (size_t)v * 82;
    int s0 = 4 * j;
    float2 t0 = (s0 + 0 <= 40) ? *(const float2*)(xv + 2 * (s0 + 0)) : make_float2(0.f, 0.f);
    float2 t1 = (s0 + 1 <= 40) ? *(const float2*)(xv + 2 * (s0 + 1)) : make_float2(0.f, 0.f);
    float2 t2 = (s0 + 2 <= 40) ? *(const float2*)(xv + 2 * (s0 + 2)) : make_float2(0.f, 0.f);
    float2 t3 = (s0 + 3 <= 40) ? *(const float2*)(xv + 2 * (s0 + 3)) : make_float2(0.f, 0.f);
    uint4 o;
    o.x = packbf(dv * t0.x, dv * t0.y);
    o.y = packbf(dv * t1.x, dv * t1.y);
    o.z = packbf(dv * t2.x, dv * t2.y);
    o.w = packbf(dv * t3.x, dv * t3.y);
    ((uint4*)(xd + (size_t)v * 48))[j] = o;
}

// --- fused GCN layer, single-wave block, csr register window ----------------
// Input rows: RU = KS*16 u32 (2 bf16 each), dis-prescaled by producer.
// agg[v] = dis[v] * ( in[v] + sum_{u->v} in[u] );  out = relu(agg @ W + b)
template <int KS, bool SCALE, bool GATE>
__global__ __launch_bounds__(64, 6) void k_fused(
    const unsigned int* __restrict__ hd, const float* __restrict__ dis,
    const int* __restrict__ rowstart, const int* __restrict__ csr,
    const unsigned short* __restrict__ Wp, const float* __restrict__ bias,
    unsigned short* __restrict__ out, const float* __restrict__ gw,
    const float* __restrict__ gb, float* __restrict__ gate, int n) {
    constexpr int RU = KS * 16;  // u32 per input row
    __shared__ unsigned int As[16 * 64];  // 16 rows x 256B (zero-padded), swizzled
    int lane = threadIdx.x & 63;
    int tile = blockIdx.x * 16;
    const bool act = (RU == 64) ? true : (lane < RU);
    const int li = act ? lane : 0;

    // csr register window: [wbase, wbase+128) lane-distributed (coalesced)
    int tl = tile < n ? tile : n;
    int th = tile + 16 < n ? tile + 16 : n;
    const int el = rowstart[tl], eh = rowstart[th];
    int wbase = el;
    unsigned int wA = (wbase + lane < eh) ? (unsigned int)csr[wbase + lane] : 0u;
    unsigned int wB = (wbase + 64 + lane < eh) ? (unsigned int)csr[wbase + 64 + lane] : 0u;

    // ---- phase 1: gather 16 rows as 4 buckets of 4 (8-edge ILP) ----
    for (int g = 0; g < 4; ++g) {
        int r = g * 4;
        int v0 = tile + r;
        unsigned int* dst0 = &As[(r + 0) * 64 + (lane ^ (((r + 0) & 7) << 2))];
        unsigned int* dst1 = &As[(r + 1) * 64 + (lane ^ (((r + 1) & 7) << 2))];
        unsigned int* dst2 = &As[(r + 2) * 64 + (lane ^ (((r + 2) & 7) << 2))];
        unsigned int* dst3 = &As[(r + 3) * 64 + (lane ^ (((r + 3) & 7) << 2))];
        if (v0 >= n) {
            *dst0 = 0u; *dst1 = 0u; *dst2 = 0u; *dst3 = 0u;
            continue;
        }
        int nv = n - v0;
        if (nv > 4) nv = 4;
        int e0 = rowstart[v0];
        int eE = rowstart[v0 + nv];
        int b1 = (nv > 1) ? rowstart[v0 + 1] : eE;
        int b2 = (nv > 2) ? rowstart[v0 + 2] : eE;
        int b3 = (nv > 3) ? rowstart[v0 + 3] : eE;

        unsigned int s0 = hd[(size_t)v0 * RU + li];
        unsigned int s1 = (nv > 1) ? hd[(size_t)(v0 + 1) * RU + li] : 0u;
        unsigned int s2 = (nv > 2) ? hd[(size_t)(v0 + 2) * RU + li] : 0u;
        unsigned int s3 = (nv > 3) ? hd[(size_t)(v0 + 3) * RU + li] : 0u;
        float a0x = b2f(s0 << 16), a0y = b2f(s0 & 0xffff0000u);
        float a1x = b2f(s1 << 16), a1y = b2f(s1 & 0xffff0000u);
        float a2x = b2f(s2 << 16), a2y = b2f(s2 & 0xffff0000u);
        float a3x = b2f(s3 << 16), a3y = b2f(s3 & 0xffff0000u);

        for (int e = e0; e < eE; e += 8) {
            // keep e..e+7 inside [wbase, wbase+128)
            while (e + 8 > wbase + 128) {
                wbase += 64;
                wA = wB;
                wB = (wbase + 64 + lane < eh) ? (unsigned int)csr[wbase + 64 + lane] : 0u;
            }
            int rem = eE - e;
            // indices via shfl from the register window
#define IDX(K)                                                              \
            ({                                                              \
                int ek_ = (rem > (K)) ? e + (K) : e;                        \
                int off_ = ek_ - wbase;                                     \
                (int)__shfl((int)((off_ < 64) ? wA : wB), off_ & 63);       \
            })
            int u0 = IDX(0), u1 = IDX(1), u2 = IDX(2), u3 = IDX(3);
            int u4 = IDX(4), u5 = IDX(5), u6 = IDX(6), u7 = IDX(7);
#undef IDX
            unsigned int r0v = hd[(size_t)u0 * RU + li];
            unsigned int r1v = hd[(size_t)u1 * RU + li];
            unsigned int r2v = hd[(size_t)u2 * RU + li];
            unsigned int r3v = hd[(size_t)u3 * RU + li];
            unsigned int r4v = hd[(size_t)u4 * RU + li];
            unsigned int r5v = hd[(size_t)u5 * RU + li];
            unsigned int r6v = hd[(size_t)u6 * RU + li];
            unsigned int r7v = hd[(size_t)u7 * RU + li];
#define ACC(rv, ei)                                                     \
            {                                                           \
                float fx = b2f((rv) << 16), fy = b2f((rv) & 0xffff0000u); \
                if ((ei) < b1) { a0x += fx; a0y += fy; }                \
                else if ((ei) < b2) { a1x += fx; a1y += fy; }           \
                else if ((ei) < b3) { a2x += fx; a2y += fy; }           \
                else { a3x += fx; a3y += fy; }                          \
            }
            ACC(r0v, e)
            if (rem > 1) ACC(r1v, e + 1)
            if (rem > 2) ACC(r2v, e + 2)
            if (rem > 3) ACC(r3v, e + 3)
            if (rem > 4) ACC(r4v, e + 4)
            if (rem > 5) ACC(r5v, e + 5)
            if (rem > 6) ACC(r6v, e + 6)
            if (rem > 7) ACC(r7v, e + 7)
#undef ACC
        }

        float d0 = dis[v0];
        float d1 = (nv > 1) ? dis[v0 + 1] : 0.f;
        float d2 = (nv > 2) ? dis[v0 + 2] : 0.f;
        float d3 = (nv > 3) ? dis[v0 + 3] : 0.f;
        *dst0 = act ? packbf(d0 * a0x, d0 * a0y) : 0u;
        *dst1 = (act && nv > 1) ? packbf(d1 * a1x, d1 * a1y) : 0u;
        *dst2 = (act && nv > 2) ? packbf(d2 * a2x, d2 * a2y) : 0u;
        *dst3 = (act && nv > 3) ? packbf(d3 * a3x, d3 * a3y) : 0u;
    }
    // single wave: LDS writes visible after s_waitcnt; no barrier needed

    // ---- phase 2: MFMA on the 16-row tile ----
    int r0 = lane & 15, ch = lane >> 4;
    const unsigned int* arow = &As[r0 << 6];
    f32x4 acc[8];
#pragma unroll
    for (int ct = 0; ct < 8; ++ct) acc[ct] = (f32x4){0.f, 0.f, 0.f, 0.f};
#pragma unroll
    for (int m = 0; m < KS; ++m) {
        int slot = (ch + 4 * m) ^ (r0 & 7);
        short8 a = *(const short8*)(arow + slot * 4);
        const short8* wf = (const short8*)Wp + ((size_t)(m * 8) * 64 + lane);
#pragma unroll
        for (int ct = 0; ct < 8; ++ct) {
            short8 b = wf[ct * 64];
            acc[ct] = __builtin_amdgcn_mfma_f32_16x16x32_bf16(a, b, acc[ct], 0, 0, 0);
        }
    }

    // ---- epilogue ----
    float bbv[8], gwv[8];
#pragma unroll
    for (int ct = 0; ct < 8; ++ct) {
        bbv[ct] = bias[ct * 16 + r0];
        if (GATE) gwv[ct] = gw[ct * 16 + r0];
    }
    float gbv = GATE ? gb[0] : 0.f;
    int rbase = tile + (ch << 2);
#pragma unroll
    for (int reg = 0; reg < 4; ++reg) {
        int row = rbase + reg;
        bool ok = row < n;
        float dv = (SCALE && ok) ? dis[row] : 1.f;
        float gp = 0.f;
#pragma unroll
        for (int ct = 0; ct < 8; ++ct) {
            float o = fmaxf(acc[ct][reg] + bbv[ct], 0.f);
            if (GATE) gp = fmaf(o, gwv[ct], gp);
            if (ok) out[(size_t)row * 128 + ct * 16 + r0] = f2b(SCALE ? o * dv : o);
        }
        if (GATE) {
            gp += __shfl_xor(gp, 1);
            gp += __shfl_xor(gp, 2);
            gp += __shfl_xor(gp, 4);
            gp += __shfl_xor(gp, 8);
            if (r0 == 0 && ok) gate[row] = gp + gbv;
        }
    }
}

// --- attention pooling: one wave per graph, inline bounds, ILP-4 sum --------
__global__ __launch_bounds__(256) void k_pool(const unsigned short* __restrict__ h,
                                              const float* __restrict__ gate,
                                              const int* __restrict__ batch,
                                              float* __restrict__ emb, int n, int B) {
    int wid = (blockIdx.x * blockDim.x + threadIdx.x) >> 6;
    int lane = threadIdx.x & 63;
    if (wid >= B) return;
    int bnd = 0;
    if (lane < 2) {
        int g = wid + lane;
        int lo = 0, hi = n;
        while (lo < hi) {
            int mid = (lo + hi) >> 1;
            if (batch[mid] < g) lo = mid + 1;
            else hi = mid;
        }
        bnd = lo;
    }
    int s = __shfl(bnd, 0), e2 = __shfl(bnd, 1);
    float* ev2 = emb + (size_t)wid * 128 + lane * 2;
    if (s >= e2) {
        ev2[0] = 0.f;
        ev2[1] = 0.f;
        return;
    }
    float m = -INFINITY;
    for (int v = s + lane; v < e2; v += 64) m = fmaxf(m, gate[v]);
#pragma unroll
    for (int off = 32; off; off >>= 1) m = fmaxf(m, __shfl_xor(m, off));
    float a0 = 0.f, a1 = 0.f, den = 0.f;
    const unsigned int* h32 = (const unsigned int*)h;
    int v = s;
    for (; v + 4 <= e2; v += 4) {
        float g0 = gate[v], g1 = gate[v + 1], g2 = gate[v + 2], g3 = gate[v + 3];
        unsigned int h0 = h32[(size_t)(v + 0) * 64 + lane];
        unsigned int h1 = h32[(size_t)(v + 1) * 64 + lane];
        unsigned int h2 = h32[(size_t)(v + 2) * 64 + lane];
        unsigned int h3 = h32[(size_t)(v + 3) * 64 + lane];
        float e0 = __expf(g0 - m), e1 = __expf(g1 - m);
        float e2v = __expf(g2 - m), e3 = __expf(g3 - m);
        den += (e0 + e1) + (e2v + e3);
        a0 = fmaf(e0, b2f(h0 << 16), a0);
        a1 = fmaf(e0, b2f(h0 & 0xffff0000u), a1);
        a0 = fmaf(e1, b2f(h1 << 16), a0);
        a1 = fmaf(e1, b2f(h1 & 0xffff0000u), a1);
        a0 = fmaf(e2v, b2f(h2 << 16), a0);
        a1 = fmaf(e2v, b2f(h2 & 0xffff0000u), a1);
        a0 = fmaf(e3, b2f(h3 << 16), a0);
        a1 = fmaf(e3, b2f(h3 & 0xffff0000u), a1);
    }
    for (; v < e2; ++v) {
        float ev = __expf(gate[v] - m);
        den += ev;
        unsigned int hv = h32[(size_t)v * 64 + lane];
        a0 = fmaf(ev, b2f(hv << 16), a0);
        a1 = fmaf(ev, b2f(hv & 0xffff0000u), a1);
    }
    float inv = 1.f / den;
    ev2[0] = a0 * inv;
    ev2[1] = a1 * inv;
}

// --- final projection: 32 graphs per block ----------------------------------
__global__ __launch_bounds__(256) void k_proj(const float* __restrict__ emb,
                                              const float* __restrict__ pw,
                                              const float* __restrict__ pb,
                                              float* __restrict__ out, int B) {
    __shared__ float es[32][128];
    int g0 = blockIdx.x * 32;
    int t = threadIdx.x;
    for (int i = t; i < 1024; i += 256) {
        int g = g0 + (i >> 5);
        float4 val = (g < B) ? ((const float4*)emb)[(size_t)g * 32 + (i & 31)]
                             : make_float4(0.f, 0.f, 0.f, 0.f);
        *(float4*)&es[i >> 5][(i & 31) * 4] = val;
    }
    __syncthreads();
    float acc[32];
#pragma unroll
    for (int i = 0; i < 32; ++i) acc[i] = 0.f;
    for (int k = 0; k < 128; ++k) {
        float wv = pw[k * 256 + t];
#pragma unroll
        for (int i = 0; i < 32; ++i) acc[i] = fmaf(es[i][k], wv, acc[i]);
    }
    float b = pb[t];
#pragma unroll
    for (int i = 0; i < 32; ++i) {
        int g = g0 + i;
        if (g < B) out[(size_t)g * 256 + t] = acc[i] + b;
    }
}

// ---------------------------------------------------------------------------
extern "C" void kernel_launch(void* const* d_in, const int* in_sizes, int n_in,
                              void* d_out, int out_size, void* d_ws, size_t ws_size,
                              hipStream_t stream) {
    const float* x = (const float*)d_in[0];
    const int* ei = (const int*)d_in[1];
    const int* batch = (const int*)d_in[2];
    const float* W0 = (const float*)d_in[3];
    const float* b0 = (const float*)d_in[4];
    const float* W1 = (const float*)d_in[5];
    const float* b1 = (const float*)d_in[6];
    const float* W2 = (const float*)d_in[7];
    const float* b2 = (const float*)d_in[8];
    const float* gw = (const float*)d_in[9];
    const float* gb = (const float*)d_in[10];
    const float* pw = (const float*)d_in[11];
    const float* pb = (const float*)d_in[12];
    float* out = (float*)d_out;

    const int N = in_sizes[2];
    const int E = in_sizes[1] / 2;
    const int B = out_size / 256;
    (void)n_in;

    const int* esrc = ei;
    const int* edst = ei + E;

    char* p = (char*)d_ws;
    auto carve = [&](size_t bytes) {
        char* r = p;
        p += (bytes + 255) & ~(size_t)255;
        return r;
    };
    unsigned int* xd = (unsigned int*)carve((size_t)N * 48 * 4);
    unsigned int* hA = (unsigned int*)carve((size_t)N * 64 * 4);
    unsigned int* hB = (unsigned int*)carve((size_t)N * 64 * 4);
    float* emb = (float*)carve((size_t)B * 128 * 4);
    int* csr_src = (int*)carve((size_t)E * 4);
    float* dis = (float*)carve((size_t)N * 4);
    int* cnt = (int*)carve((size_t)2 * N * 4);  // cnt + cur0 (one memset)
    int* cur0 = cnt + N;
    int* rowstart = (int*)carve((size_t)(N + 1) * 4);
    float* gate = (float*)carve((size_t)N * 4);
    int* bsum = (int*)carve((size_t)4096 * 4);
    unsigned short* wp0 = (unsigned short*)carve((size_t)3 * 512 * 8 * 2);
    unsigned short* wp1 = (unsigned short*)carve((size_t)4 * 512 * 8 * 2);
    unsigned short* wp2 = (unsigned short*)carve((size_t)4 * 512 * 8 * 2);
    if ((size_t)(p - (char*)d_ws) > ws_size) return;

    const int nb = (N + 2047) / 2048;  // 245 (<= 256 required by k_scan3)

    hipMemsetAsync(cnt, 0, (size_t)2 * N * 4, stream);
    k_count<<<(E + 255) / 256, 256, 0, stream>>>(edst, cnt, E);
    k_scan1<<<nb, 256, 0, stream>>>(cnt, rowstart + 1, bsum, dis, N);
    k_scan3<<<nb, 256, 0, stream>>>(rowstart, bsum, N);
    k_fill<<<(E + 255) / 256, 256, 0, stream>>>(esrc, edst, rowstart, cur0, csr_src, E);
    k_cvtw3<<<22, 256, 0, stream>>>(W0, W1, W2, wp0, wp1, wp2);
    k_xd<<<(N * 12 + 255) / 256, 256, 0, stream>>>(x, dis, xd, N);

    const int fb = (N + 15) / 16;  // single-wave blocks, 16 rows each

    // layer 0: xd -> hA (bf16, dis-prescaled)
    k_fused<3, true, false><<<fb, 64, 0, stream>>>(
        xd, dis, rowstart, csr_src, wp0, b0, (unsigned short*)hA,
        nullptr, nullptr, nullptr, N);
    // layer 1: hA -> hB (bf16, dis-prescaled)
    k_fused<4, true, false><<<fb, 64, 0, stream>>>(
        hA, dis, rowstart, csr_src, wp1, b1, (unsigned short*)hB,
        nullptr, nullptr, nullptr, N);
    // layer 2: hB -> hA (unscaled) + gate
    k_fused<4, false, true><<<fb, 64, 0, stream>>>(
        hB, dis, rowstart, csr_src, wp2, b2, (unsigned short*)hA,
        gw, gb, gate, N);

    // pooling + projection
    k_pool<<<(B + 3) / 4, 256, 0, stream>>>((const unsigned short*)hA, gate, batch,
                                            emb, N, B);
    k_proj<<<(B + 31) / 32, 256, 0, stream>>>(emb, pw, pb, out, B);
}